// Round 11
// baseline (7126.271 us; speedup 1.0000x reference)
//
#include <hip/hip_runtime.h>
#include <float.h>

#define N_PTS   50000
#define M_CENT  2048
#define K_LOC   32
#define C_CH    128

typedef unsigned long long u64;
typedef unsigned int u32;

// ------ FPS: single-block, cell-pruned, wave-owned, register-A (R11) ------
// R7-R10 (all absmax 0.0, all ~5-6K cyc/iter) isolated the invariant cost:
// O(NC) LDS/global scan traffic in Phase A (key+bbox reads, 36-82 KB/iter)
// + C1 key scan, on the CU-shared LDS pipe. R11 removes it:
//  - cell == chunk on a REGULAR 12^3 grid -> cube bounds are index
//    arithmetic; per-lane bounds precomputed in registers; Phase A does
//    ZERO memory reads (cmax comes from registers cached by last C1).
//  - C1's single key scan (14 KB/iter) feeds both the winner reduce and
//    next iteration's A (key-hi retained in registers).
//  - 1728 = 16*108: wave w owns cells c with c%16==w at slot c/16.
//  - B keeps the R10 prefetch pipeline; ~70 active cells/iter spread ~4/wave.
// Exactness: cube-LB <= tight-bbox-LB <= true d2; skip iff 0.999*LB >=
// cmax  =>  min(dist_j, d2_ref) == dist_j bit-identically (1e-3 margin >>
// f32 rounding; proven 4x on HW). Active cells recompute d2 with exact
// reference arithmetic; ties -> min ORIGINAL idx (key = dist<<32 | ~idx).
#define G_DIM   12
#define N_CELL  (G_DIM*G_DIM*G_DIM)   // 1728 = 16 * 108
#define SLOTW   108
#define FPS1_NT 1024
#define NWAVE   (FPS1_NT/64)          // 16

__device__ __forceinline__ int cell_of(float x, float y, float z) {
  int a = (int)(x * (float)G_DIM);
  int b = (int)(y * (float)G_DIM);
  int c = (int)(z * (float)G_DIM);
  a = a < 0 ? 0 : (a > G_DIM-1 ? G_DIM-1 : a);
  b = b < 0 ? 0 : (b > G_DIM-1 ? G_DIM-1 : b);
  c = c < 0 ? 0 : (c > G_DIM-1 ? G_DIM-1 : c);
  return (a * G_DIM + b) * G_DIM + c;
}

// ---- DPP wave-wide reductions (ctrl must be a literal constant) ----
template <int CTRL>
__device__ __forceinline__ u32 dppmov_u(u32 v) {
  return (u32)__builtin_amdgcn_update_dpp((int)v, (int)v, CTRL, 0xf, 0xf, false);
}
template <int CTRL>
__device__ __forceinline__ float dppmov_f(float v) {
  return __int_as_float(
      __builtin_amdgcn_update_dpp(__float_as_int(v), __float_as_int(v),
                                  CTRL, 0xf, 0xf, false));
}
__device__ __forceinline__ float wave_max_f32(float v) {
  v = fmaxf(v, dppmov_f<0x111>(v));
  v = fmaxf(v, dppmov_f<0x112>(v));
  v = fmaxf(v, dppmov_f<0x114>(v));
  v = fmaxf(v, dppmov_f<0x118>(v));
  v = fmaxf(v, dppmov_f<0x142>(v));
  v = fmaxf(v, dppmov_f<0x143>(v));
  return __int_as_float(__builtin_amdgcn_readlane(__float_as_int(v), 63));
}
__device__ __forceinline__ u32 wave_min_u32(u32 v) {
  u32 t;
  t = dppmov_u<0x111>(v); v = v < t ? v : t;
  t = dppmov_u<0x112>(v); v = v < t ? v : t;
  t = dppmov_u<0x114>(v); v = v < t ? v : t;
  t = dppmov_u<0x118>(v); v = v < t ? v : t;
  t = dppmov_u<0x142>(v); v = v < t ? v : t;
  t = dppmov_u<0x143>(v); v = v < t ? v : t;
  return (u32)__builtin_amdgcn_readlane((int)v, 63);
}
template <int CTRL>
__device__ __forceinline__ u64 dpp_u64(u64 v) {
  u32 hi = dppmov_u<CTRL>((u32)(v >> 32));
  u32 lo = dppmov_u<CTRL>((u32)v);
  return ((u64)hi << 32) | (u64)lo;
}
__device__ __forceinline__ u64 wave_max_u64(u64 v) {
  u64 t;
  t = dpp_u64<0x111>(v); if (t > v) v = t;
  t = dpp_u64<0x112>(v); if (t > v) v = t;
  t = dpp_u64<0x114>(v); if (t > v) v = t;
  t = dpp_u64<0x118>(v); if (t > v) v = t;
  t = dpp_u64<0x142>(v); if (t > v) v = t;
  t = dpp_u64<0x143>(v); if (t > v) v = t;
  u32 rh = (u32)__builtin_amdgcn_readlane((int)(v >> 32), 63);
  u32 rl = (u32)__builtin_amdgcn_readlane((int)(v & 0xFFFFFFFFull), 63);
  return ((u64)rh << 32) | (u64)rl;
}

// ---------------- prep kernels ----------------
__global__ void init_zero_kernel(int* __restrict__ p, int n) {
  int t = blockIdx.x * blockDim.x + threadIdx.x;
  if (t < n) p[t] = 0;
}

__global__ void hist_kernel(const float* __restrict__ pos,
                            int* __restrict__ cellcnt) {
  int n = blockIdx.x * blockDim.x + threadIdx.x;
  if (n >= N_PTS) return;
  atomicAdd(&cellcnt[cell_of(pos[3*n], pos[3*n+1], pos[3*n+2])], 1);
}

__global__ __launch_bounds__(1024) void scan_kernel(
    const int* __restrict__ cellcnt, int* __restrict__ cursor,
    int2* __restrict__ rng)
{
  __shared__ int s[2048];
  const int tid = threadIdx.x;
  int c0 = (tid < N_CELL) ? cellcnt[tid] : 0;
  int c1 = (tid + 1024 < N_CELL) ? cellcnt[tid + 1024] : 0;
  s[tid] = c0; s[tid + 1024] = c1;
  __syncthreads();
  for (int off = 1; off < 2048; off <<= 1) {      // inclusive scan
    int a0 = (tid >= off) ? s[tid - off] : 0;
    int a1 = (tid + 1024 >= off) ? s[tid + 1024 - off] : 0;
    __syncthreads();
    s[tid] += a0; s[tid + 1024] += a1;
    __syncthreads();
  }
  if (tid < N_CELL) {
    int pofs = s[tid] - c0;
    cursor[tid] = pofs;
    rng[tid] = make_int2(pofs, c0);
  }
  if (tid + 1024 < N_CELL) {
    int pofs = s[tid + 1024] - c1;
    cursor[tid + 1024] = pofs;
    rng[tid + 1024] = make_int2(pofs, c1);
  }
}

__global__ void scatter_kernel(const float* __restrict__ pos,
    int* __restrict__ cursor, float4* __restrict__ spp,
    int* __restrict__ sidx)
{
  int n = blockIdx.x * blockDim.x + threadIdx.x;
  if (n >= N_PTS) return;
  float x = pos[3*n], y = pos[3*n+1], z = pos[3*n+2];
  int p = atomicAdd(&cursor[cell_of(x, y, z)], 1);
  spp[p] = make_float4(x, y, z, FLT_MAX);   // .w = running dist (ref init)
  sidx[p] = n;
}

// ---------------- the FPS kernel ----------------
__global__ __launch_bounds__(FPS1_NT) void fps_kernel(
    const float* __restrict__ pos,
    float4* __restrict__ spp, const int* __restrict__ sidx,
    const int2* __restrict__ rng, float* __restrict__ cent_out)
{
  // wave w owns cells c with c%16 == w; slot j = c/16 in [0,108)
  __shared__ u64    l_key[N_CELL];    // (maxdist_bits<<32) | ~minidx
  __shared__ int2   l_rng[N_CELL];
  __shared__ float  l_wcx[N_CELL], l_wcy[N_CELL], l_wcz[N_CELL];
  __shared__ u64    l_red[NWAVE];
  __shared__ float4 l_rco[NWAVE];
  __shared__ float4 l_winco;

  const int tid = threadIdx.x, lane = tid & 63, wv = tid >> 6;
  const int base = wv * SLOTW;

  for (int c = tid; c < N_CELL; c += FPS1_NT) {
    int p = (c & 15) * SLOTW + (c >> 4);
    int2 rc = rng[c];
    l_rng[p] = rc;
    l_key[p] = (rc.y > 0) ? (((u64)0x7F7FFFFFu) << 32) : 0ull;  // FLT_MAX hi
    l_wcx[p] = 0.f; l_wcy[p] = 0.f; l_wcz[p] = 0.f;
  }
  __syncthreads();

  // per-lane static cell cube bounds (registers; j0 = lane, j1 = lane+64)
  const float inv = 1.0f / (float)G_DIM;
  float b0lx, b0hx, b0ly, b0hy, b0lz, b0hz;
  float b1lx = 0, b1hx = 0, b1ly = 0, b1hy = 0, b1lz = 0, b1hz = 0;
  {
    int c0 = (lane << 4) + wv;
    int a = c0 / 144, r = c0 - a * 144, b = r / 12, z = r - b * 12;
    b0lx = a * inv; b0hx = (a + 1) * inv;
    b0ly = b * inv; b0hy = (b + 1) * inv;
    b0lz = z * inv; b0hz = (z + 1) * inv;
    if (lane < SLOTW - 64) {
      int c1 = ((lane + 64) << 4) + wv;
      a = c1 / 144; r = c1 - a * 144; b = r / 12; z = r - b * 12;
      b1lx = a * inv; b1hx = (a + 1) * inv;
      b1ly = b * inv; b1hy = (b + 1) * inv;
      b1lz = z * inv; b1hz = (z + 1) * inv;
    }
  }
  const int p0 = base + lane;
  const int p1 = base + 64 + lane;          // valid for lane < 44
  float kh0 = __uint_as_float((u32)(l_key[p0] >> 32));
  float kh1 = (lane < SLOTW - 64) ? __uint_as_float((u32)(l_key[p1] >> 32))
                                  : 0.f;

  // iteration 0 centroid = point 0 (deterministic start, matches reference)
  float cx = pos[0], cy = pos[1], cz = pos[2];

  for (int i = 0; i < M_CENT; i++) {
    if (tid == 0) {
      cent_out[3*i+0] = cx; cent_out[3*i+1] = cy; cent_out[3*i+2] = cz;
    }
    if (i == M_CENT - 1) break;      // last winner never consumed (uniform)

    // ---- Phase A (registers only): cube-LB prune, 2 ballots ----
    u64 m0, m1;
    {
      float ax = fmaxf(fmaxf(b0lx - cx, cx - b0hx), 0.f);
      float ay = fmaxf(fmaxf(b0ly - cy, cy - b0hy), 0.f);
      float az = fmaxf(fmaxf(b0lz - cz, cz - b0hz), 0.f);
      float LB = (ax*ax + ay*ay + az*az) * 0.999f;   // conservative margin
      m0 = __ballot(LB < kh0);       // empty cell: kh0=0 -> never active
      ax = fmaxf(fmaxf(b1lx - cx, cx - b1hx), 0.f);
      ay = fmaxf(fmaxf(b1ly - cy, cy - b1hy), 0.f);
      az = fmaxf(fmaxf(b1lz - cz, cz - b1hz), 0.f);
      LB = (ax*ax + ay*ay + az*az) * 0.999f;
      m1 = __ballot((lane < SLOTW - 64) && (LB < kh1));
    }

    // ---- Phase B (wave-private, prefetch-pipelined) ----
    auto pop = [&]() -> int {        // wave-uniform (masks from ballots)
      if (m0) { int b = __ffsll((long long)m0)-1; m0 &= m0-1; return b; }
      if (m1) { int b = __ffsll((long long)m1)-1; m1 &= m1-1; return b+64; }
      return -1;
    };
    int j_c = pop();
    int2 rc_c = make_int2(0, 0);
    float4 P_c = make_float4(0,0,0,0);
    if (j_c >= 0) {
      rc_c = l_rng[base + j_c];
      if (lane < rc_c.y) P_c = spp[rc_c.x + lane];
    }
    while (j_c >= 0) {
      int j_n = pop();               // prefetch next cell during reduce
      int2 rc_n = make_int2(0, 0);
      float4 P_n = make_float4(0,0,0,0);
      if (j_n >= 0) {
        rc_n = l_rng[base + j_n];
        if (lane < rc_n.y) P_n = spp[rc_n.x + lane];
      }
      int p_c = base + j_c;
      if (rc_c.y <= 64) {
        // fast path: one point per lane
        bool v = lane < rc_c.y;
        int g = rc_c.x + lane;
        float dm = -1.f;
        if (v) {
          // exact reference arithmetic: no FMA, ((dx^2+dy^2)+dz^2)
          float dx = __fsub_rn(P_c.x, cx);
          float dy = __fsub_rn(P_c.y, cy);
          float dz = __fsub_rn(P_c.z, cz);
          float d2 = __fadd_rn(__fadd_rn(__fmul_rn(dx,dx), __fmul_rn(dy,dy)),
                               __fmul_rn(dz,dz));
          float dn = fminf(P_c.w, d2);
          if (dn < P_c.w) ((float*)(spp + g))[3] = dn;
          dm = dn;
        }
        float wmax = wave_max_f32(dm);     // >= 0 (cell non-empty)
        u32 hb = __float_as_uint(wmax);
        u64 tb = __ballot(dm == wmax);
        if (__popcll(tb) == 1) {           // unique argmax lane (common)
          if (dm == wmax) {
            u32 mi = (u32)sidx[g];         // lazy orig-idx load (1 lane)
            l_key[p_c] = ((u64)hb << 32) | (u64)(~mi);
            l_wcx[p_c] = P_c.x; l_wcy[p_c] = P_c.y; l_wcz[p_c] = P_c.z;
          }
        } else {                           // exact tie fallback (rare)
          u32 cand = (dm == wmax) ? (u32)sidx[g] : 0xFFFFFFFFu;
          u32 minidx = wave_min_u32(cand);
          if (dm == wmax && cand == minidx) {
            l_key[p_c] = ((u64)hb << 32) | (u64)(~minidx);
            l_wcx[p_c] = P_c.x; l_wcy[p_c] = P_c.y; l_wcz[p_c] = P_c.z;
          }
        }
      } else {
        // slow generic path (cells > 64 pts: essentially never, but exact)
        float bd = -1.f; u32 bi = 0xFFFFFFFFu;
        float bx = 0.f, by = 0.f, bz = 0.f;
        for (int t0 = 0; t0 < rc_c.y; t0 += 64) {
          int gg = rc_c.x + t0 + lane;
          bool vv = t0 + lane < rc_c.y;
          float4 P = vv ? spp[gg] : make_float4(0,0,0,0);
          if (vv) {
            float dx = __fsub_rn(P.x, cx);
            float dy = __fsub_rn(P.y, cy);
            float dz = __fsub_rn(P.z, cz);
            float d2 = __fadd_rn(__fadd_rn(__fmul_rn(dx,dx), __fmul_rn(dy,dy)),
                                 __fmul_rn(dz,dz));
            float dn = fminf(P.w, d2);
            if (dn < P.w) ((float*)(spp + gg))[3] = dn;
            if (dn > bd) { bd = dn; bi = (u32)sidx[gg]; bx=P.x; by=P.y; bz=P.z; }
            else if (dn == bd) {
              u32 s = (u32)sidx[gg];
              if (s < bi) { bi = s; bx=P.x; by=P.y; bz=P.z; }
            }
          }
        }
        float wmax = wave_max_f32(bd);
        u32 hb = __float_as_uint(wmax);
        u32 cand = (bd == wmax) ? bi : 0xFFFFFFFFu;
        u32 minidx = wave_min_u32(cand);
        if (bd == wmax && cand == minidx) {
          l_key[p_c] = ((u64)hb << 32) | (u64)(~minidx);
          l_wcx[p_c] = bx; l_wcy[p_c] = by; l_wcz[p_c] = bz;
        }
      }
      j_c = j_n; rc_c = rc_n; P_c = P_n;
    }

    // ---- Phase C1 (wave-private): scan own keys; cache hi for next A ----
    {
      u64 k0 = l_key[p0];
      u64 k1 = (lane < SLOTW - 64) ? l_key[p1] : 0ull;
      kh0 = __uint_as_float((u32)(k0 >> 32));
      if (lane < SLOTW - 64) kh1 = __uint_as_float((u32)(k1 >> 32));
      u64 kb; int pb;
      if (k1 > k0) { kb = k1; pb = p1; } else { kb = k0; pb = p0; }
      float kf = __uint_as_float((u32)(kb >> 32));
      float km = wave_max_f32(kf);
      u64 cm = __ballot(kf == km);
      if (__popcll(cm) == 1) {           // unique dist-max (common)
        if (kf == km) {
          l_red[wv] = kb;
          l_rco[wv] = make_float4(l_wcx[pb], l_wcy[pb], l_wcz[pb], 0.f);
        }
      } else {                           // exact tie fallback (rare)
        u64 km64 = wave_max_u64(kb);
        u64 bm = __ballot(kb == km64);
        if (lane == __ffsll((long long)bm) - 1) {
          l_red[wv] = kb;
          l_rco[wv] = make_float4(l_wcx[pb], l_wcy[pb], l_wcz[pb], 0.f);
        }
      }
    }
    __syncthreads();
    // ---- Phase C2: wave0 reduces the 16 wave winners ----
    if (wv == 0) {
      u64 k = (lane < NWAVE) ? l_red[lane] : 0ull;
      u64 gm = wave_max_u64(k);
      u64 bm = __ballot(k == gm);
      if (lane == __ffsll((long long)bm) - 1) l_winco = l_rco[lane];
    }
    __syncthreads();
    cx = l_winco.x; cy = l_winco.y; cz = l_winco.z;
  }
}

// ---------------- Ball query ----------------
#define BQ_NT  256
#define BQ_CAP 2048   // expected ~209 candidates/centroid; huge safety margin

__global__ __launch_bounds__(BQ_NT) void ballq_kernel(
    const float* __restrict__ pos,
    const float* __restrict__ cent,   // centroid coords (from d_out)
    int* __restrict__ nbr,            // [M_CENT*K_LOC]
    int* __restrict__ nsel)           // [M_CENT]
{
  __shared__ float s_d2[BQ_CAP];
  __shared__ int   s_idx[BQ_CAP];
  __shared__ int   s_count;
  __shared__ u64   s_red[BQ_NT/64];
  __shared__ u64   s_win;

  const int m = blockIdx.x, tid = threadIdx.x;
  if (tid == 0) s_count = 0;
  __syncthreads();
  const float cx = cent[3*m+0], cy = cent[3*m+1], cz = cent[3*m+2];

  for (int n = tid; n < N_PTS; n += BQ_NT) {
    float dx = __fsub_rn(cx, pos[3*n+0]);
    float dy = __fsub_rn(cy, pos[3*n+1]);
    float dz = __fsub_rn(cz, pos[3*n+2]);
    float d2 = __fadd_rn(__fadd_rn(__fmul_rn(dx,dx), __fmul_rn(dy,dy)),
                         __fmul_rn(dz,dz));
    if (d2 <= 0.01f) {   // same f32 value as (float)(0.1*0.1)
      int p = atomicAdd(&s_count, 1);
      if (p < BQ_CAP) { s_d2[p] = d2; s_idx[p] = n; }
    }
  }
  __syncthreads();
  int cnt = s_count; if (cnt > BQ_CAP) cnt = BQ_CAP;
  int ns = cnt < K_LOC ? cnt : K_LOC;

  // exact top_k semantics: k smallest d2, ties -> smaller index
  for (int sel = 0; sel < ns; sel++) {
    u64 best = ~0ull;
    for (int p = tid; p < cnt; p += BQ_NT) {
      u64 pk = ((u64)__float_as_uint(s_d2[p]) << 32) | (u64)(u32)s_idx[p];
      if (pk < best) best = pk;
    }
#pragma unroll
    for (int off = 32; off >= 1; off >>= 1) {
      u64 o = __shfl_down(best, off, 64);
      if (o < best) best = o;
    }
    if ((tid & 63) == 0) s_red[tid >> 6] = best;
    __syncthreads();
    if (tid < 64) {
      best = (tid < BQ_NT/64) ? s_red[tid] : ~0ull;
#pragma unroll
      for (int off = 2; off >= 1; off >>= 1) {
        u64 o = __shfl_down(best, off, 64);
        if (o < best) best = o;
      }
      if (tid == 0) s_win = best;
    }
    __syncthreads();
    int widx = (int)(u32)(s_win & 0xFFFFFFFFull);
    if (tid == 0) nbr[m*K_LOC + sel] = widx;
    for (int p = tid; p < cnt; p += BQ_NT) {
      if (s_idx[p] == widx) s_d2[p] = FLT_MAX;   // remove winner
    }
    __syncthreads();
  }
  if (tid == 0) nsel[m] = ns;
}

// ---------------- Gather + max-pool + channel mix ----------------
// Max over the valid selected set == reference (fallback idx is the nearest
// valid neighbor, already a member of the set).
__global__ __launch_bounds__(C_CH) void pool_mix_kernel(
    const float* __restrict__ fs,   // (N,128,1)
    const float* __restrict__ fv,   // (N,128,3)
    const float* __restrict__ Ws,
    const float* __restrict__ Wv,
    const float* __restrict__ bs,
    const float* __restrict__ bv,
    const int* __restrict__ nbr,
    const int* __restrict__ nsel,
    float* __restrict__ out_s,      // (M,128,1)
    float* __restrict__ out_v)      // (M,128,3)
{
  __shared__ float ps[C_CH];
  __shared__ float pv[C_CH*3];
  const int m = blockIdx.x, o = threadIdx.x;
  const int ns = nsel[m];
  float mS = -FLT_MAX, m0 = -FLT_MAX, m1 = -FLT_MAX, m2 = -FLT_MAX;
  for (int j = 0; j < ns; j++) {
    int n = nbr[m*K_LOC + j];
    mS = fmaxf(mS, fs[(size_t)n*C_CH + o]);
    const float* r = fv + (size_t)n*(C_CH*3) + 3*o;
    m0 = fmaxf(m0, r[0]); m1 = fmaxf(m1, r[1]); m2 = fmaxf(m2, r[2]);
  }
  ps[o] = mS; pv[3*o+0] = m0; pv[3*o+1] = m1; pv[3*o+2] = m2;
  __syncthreads();
  float aS = bs[o];
  float a0 = bv[o], a1 = bv[o], a2 = bv[o];
  for (int cc = 0; cc < C_CH; cc++) {
    float w1 = Ws[cc*C_CH + o];
    float w2 = Wv[cc*C_CH + o];
    aS = fmaf(ps[cc], w1, aS);
    a0 = fmaf(pv[3*cc+0], w2, a0);
    a1 = fmaf(pv[3*cc+1], w2, a1);
    a2 = fmaf(pv[3*cc+2], w2, a2);
  }
  out_s[(size_t)m*C_CH + o] = aS;
  float* ov = out_v + (size_t)m*(C_CH*3) + 3*o;
  ov[0] = a0; ov[1] = a1; ov[2] = a2;
}

extern "C" void kernel_launch(void* const* d_in, const int* in_sizes, int n_in,
                              void* d_out, int out_size, void* d_ws, size_t ws_size,
                              hipStream_t stream) {
  (void)in_sizes; (void)n_in; (void)out_size; (void)ws_size;
  const float* pos = (const float*)d_in[0];
  const float* fs  = (const float*)d_in[1];
  const float* fv  = (const float*)d_in[2];
  const float* Ws  = (const float*)d_in[3];
  const float* Wv  = (const float*)d_in[4];
  const float* bs  = (const float*)d_in[5];
  const float* bv  = (const float*)d_in[6];

  float* out      = (float*)d_out;
  float* cent_out = out;                               // 2048*3
  float* out_s    = out + 3*M_CENT;                    // 2048*128
  float* out_v    = out + 3*M_CENT + M_CENT*C_CH;      // 2048*128*3

  // workspace layout (all offsets 256B-aligned)
  char* ws = (char*)d_ws;
  size_t off = 0;
  float4* spp  = (float4*)(ws + off); off += (size_t)50176 * 16;   // 802816
  int*   sidx  = (int*)  (ws + off);  off += (size_t)50176 * 4;
  int*   cellcnt = (int*)(ws + off);  off += 2048 * 4;
  int*   cursor  = (int*)(ws + off);  off += 2048 * 4;
  int2*  rng     = (int2*)(ws + off); off += 2048 * 8;
  int*   nbr     = (int*)(ws + off); off += (size_t)M_CENT * K_LOC * 4;
  int*   nsel    = (int*)(ws + off); off += (size_t)M_CENT * 4;

  // zero cellcnt + cursor (contiguous: 2048+2048 ints)
  init_zero_kernel<<<(4096 + 255)/256, 256, 0, stream>>>(cellcnt, 4096);
  hist_kernel<<<(N_PTS + 255)/256, 256, 0, stream>>>(pos, cellcnt);
  scan_kernel<<<1, 1024, 0, stream>>>(cellcnt, cursor, rng);
  scatter_kernel<<<(N_PTS + 255)/256, 256, 0, stream>>>(pos, cursor, spp, sidx);
  fps_kernel<<<1, FPS1_NT, 0, stream>>>(pos, spp, sidx, rng, cent_out);
  ballq_kernel<<<M_CENT, BQ_NT, 0, stream>>>(pos, cent_out, nbr, nsel);
  pool_mix_kernel<<<M_CENT, C_CH, 0, stream>>>(fs, fv, Ws, Wv, bs, bv,
                                               nbr, nsel, out_s, out_v);
}